// Round 4
// baseline (14746.516 us; speedup 1.0000x reference)
//
#include <hip/hip_runtime.h>
#include <cstddef>

#define NN 883
#define BB 64
#define TT 12
#define EMB 10
#define KPAD 896  // 883 padded up to multiple of 128 (and of 32)

typedef short short8 __attribute__((ext_vector_type(8)));
typedef _Float16 half8 __attribute__((ext_vector_type(8)));
typedef float f32x4 __attribute__((ext_vector_type(4)));

__device__ __forceinline__ void split_f16(float v, _Float16* hp, _Float16* lp) {
  _Float16 h = (_Float16)v;
  *hp = h;
  *lp = (_Float16)(v - (float)h);
}

// -------- adjacency: A = softmax(relu(E E^T), axis=1), emitted as f16 hi/lo --
__global__ __launch_bounds__(256) void adj_kernel(const float* __restrict__ E,
                                                  _Float16* __restrict__ Ah,
                                                  _Float16* __restrict__ Al) {
  const int n = blockIdx.x;
  const int tid = threadIdx.x;
  __shared__ float sE[EMB];
  __shared__ float sred[256];
  if (tid < EMB) sE[tid] = E[n * EMB + tid];
  __syncthreads();
  float d[4];
  float lmax = 0.0f;
#pragma unroll
  for (int q = 0; q < 4; ++q) {
    int m = tid + q * 256;
    d[q] = 0.0f;
    if (m < NN) {
      float s = 0.0f;
#pragma unroll
      for (int e = 0; e < EMB; ++e) s += sE[e] * E[m * EMB + e];
      d[q] = fmaxf(s, 0.0f);
      lmax = fmaxf(lmax, d[q]);
    }
  }
  sred[tid] = lmax;
  __syncthreads();
  for (int s = 128; s > 0; s >>= 1) {
    if (tid < s) sred[tid] = fmaxf(sred[tid], sred[tid + s]);
    __syncthreads();
  }
  const float mx = sred[0];
  __syncthreads();
  float lsum = 0.0f;
#pragma unroll
  for (int q = 0; q < 4; ++q) {
    int m = tid + q * 256;
    if (m < NN) {
      d[q] = expf(d[q] - mx);
      lsum += d[q];
    }
  }
  sred[tid] = lsum;
  __syncthreads();
  for (int s = 128; s > 0; s >>= 1) {
    if (tid < s) sred[tid] += sred[tid + s];
    __syncthreads();
  }
  const float inv = 1.0f / sred[0];
#pragma unroll
  for (int q = 0; q < 4; ++q) {
    int m = tid + q * 256;
    if (m < KPAD) {
      float v = (m < NN) ? d[q] * inv : 0.0f;
      split_f16(v, &Ah[(size_t)n * KPAD + m], &Al[(size_t)n * KPAD + m]);
    }
  }
}

// -------- 3-term split-f16 MFMA GEMM; output written as split f16 (Gh/Gl) ----
// 128x128 block tile, 4 waves 2x2, each wave 64x64 via 4x4 MFMA 16x16x32.
__global__ __launch_bounds__(256) void mfma_gemm3(const _Float16* __restrict__ Ah,
                                                  const _Float16* __restrict__ Al,
                                                  const _Float16* __restrict__ Xh,
                                                  const _Float16* __restrict__ Xl,
                                                  _Float16* __restrict__ Gh,
                                                  _Float16* __restrict__ Gl, int L) {
  __shared__ _Float16 sA[2][128][40];    // [hi/lo][m][k], pad 32->40
  __shared__ _Float16 sX[2][4][128][8];  // [hi/lo][k-octet][l][k&7]
  const int tid = threadIdx.x;
  const int lane = tid & 63;
  const int wid = tid >> 6;
  const int wm = (wid >> 1) * 64, wn = (wid & 1) * 64;
  const int bm = blockIdx.y * 128;
  const int bl = blockIdx.x * 128;
  const int l15 = lane & 15, l4 = lane >> 4;

  f32x4 acc[4][4] = {};

  const int xlp = (tid & 63) * 2;  // l-pair this thread stages
  const int xko = tid >> 6;        // k-octet this thread stages

  for (int k0 = 0; k0 < KPAD; k0 += 32) {
    __syncthreads();
#pragma unroll
    for (int p = 0; p < 2; ++p) {
      int i = tid + p * 256;
      int m = i >> 2, k8 = (i & 3) * 8;
      *(half8*)&sA[0][m][k8] = *(const half8*)&Ah[(size_t)(bm + m) * KPAD + k0 + k8];
      *(half8*)&sA[1][m][k8] = *(const half8*)&Al[(size_t)(bm + m) * KPAD + k0 + k8];
    }
    {
      int gl = bl + xlp;
      int kb = k0 + xko * 8;
#pragma unroll
      for (int buf = 0; buf < 2; ++buf) {
        const _Float16* Xp = buf ? Xl : Xh;
        unsigned int v[8];
        if (gl < L) {
#pragma unroll
          for (int j = 0; j < 8; ++j)
            v[j] = *(const unsigned int*)&Xp[(size_t)(kb + j) * L + gl];
        } else {
#pragma unroll
          for (int j = 0; j < 8; ++j) v[j] = 0u;
        }
        short8 lo, hi;
#pragma unroll
        for (int j = 0; j < 8; ++j) {
          lo[j] = (short)(v[j] & 0xFFFFu);
          hi[j] = (short)(v[j] >> 16);
        }
        *(short8*)&sX[buf][xko][xlp][0] = lo;
        *(short8*)&sX[buf][xko][xlp + 1][0] = hi;
      }
    }
    __syncthreads();
    half8 afh[4], afl[4], bfh[4], bfl[4];
#pragma unroll
    for (int mi = 0; mi < 4; ++mi) {
      afh[mi] = *(half8*)&sA[0][wm + mi * 16 + l15][l4 * 8];
      afl[mi] = *(half8*)&sA[1][wm + mi * 16 + l15][l4 * 8];
    }
#pragma unroll
    for (int ni = 0; ni < 4; ++ni) {
      bfh[ni] = *(half8*)&sX[0][l4][wn + ni * 16 + l15][0];
      bfl[ni] = *(half8*)&sX[1][l4][wn + ni * 16 + l15][0];
    }
#pragma unroll
    for (int mi = 0; mi < 4; ++mi)
#pragma unroll
      for (int ni = 0; ni < 4; ++ni) {
        acc[mi][ni] = __builtin_amdgcn_mfma_f32_16x16x32_f16(afh[mi], bfh[ni],
                                                             acc[mi][ni], 0, 0, 0);
        acc[mi][ni] = __builtin_amdgcn_mfma_f32_16x16x32_f16(afh[mi], bfl[ni],
                                                             acc[mi][ni], 0, 0, 0);
        acc[mi][ni] = __builtin_amdgcn_mfma_f32_16x16x32_f16(afl[mi], bfh[ni],
                                                             acc[mi][ni], 0, 0, 0);
      }
  }
#pragma unroll
  for (int mi = 0; mi < 4; ++mi) {
    int row0 = bm + wm + mi * 16 + l4 * 4;
#pragma unroll
    for (int ni = 0; ni < 4; ++ni) {
      int col = bl + wn + ni * 16 + l15;
      if (col < L) {
#pragma unroll
        for (int r = 0; r < 4; ++r) {
          int row = row0 + r;
          if (row < NN)
            split_f16(acc[mi][ni][r], &Gh[(size_t)row * L + col],
                      &Gl[(size_t)row * L + col]);
        }
      }
    }
  }
}

// ---------------- concat builders (node-major [n][b][c], f16 hi/lo out) ------
__global__ __launch_bounds__(256) void concat_l0_a(const float* __restrict__ src,
                                                   const float* __restrict__ h0,
                                                   _Float16* __restrict__ Xh,
                                                   _Float16* __restrict__ Xl, int t) {
  int i = blockIdx.x * 256 + threadIdx.x;
  if (i >= NN * BB * 65) return;
  int c = i % 65;
  int nb = i / 65;
  int b = nb & 63;
  int n = nb >> 6;
  float v = (c == 0) ? src[((size_t)b * TT + t) * NN + n]
                     : h0[(size_t)nb * 64 + (c - 1)];
  split_f16(v, &Xh[i], &Xl[i]);
}

__global__ __launch_bounds__(256) void concat_l0_b(const float* __restrict__ src,
                                                   const float* __restrict__ h0,
                                                   const float* __restrict__ ZR,
                                                   _Float16* __restrict__ Xh,
                                                   _Float16* __restrict__ Xl, int t) {
  int i = blockIdx.x * 256 + threadIdx.x;
  if (i >= NN * BB * 65) return;
  int c = i % 65;
  int nb = i / 65;
  int b = nb & 63;
  int n = nb >> 6;
  float v = (c == 0) ? src[((size_t)b * TT + t) * NN + n]
                     : ZR[(size_t)nb * 128 + (c - 1)] * h0[(size_t)nb * 64 + (c - 1)];
  split_f16(v, &Xh[i], &Xl[i]);
}

__global__ __launch_bounds__(256) void concat_l1_a(const float* __restrict__ h0,
                                                   const float* __restrict__ h1,
                                                   _Float16* __restrict__ Xh,
                                                   _Float16* __restrict__ Xl) {
  int i = blockIdx.x * 256 + threadIdx.x;
  if (i >= NN * BB * 128) return;
  int c = i & 127;
  int nb = i >> 7;
  float v = (c < 64) ? h0[(size_t)nb * 64 + c] : h1[(size_t)nb * 64 + (c - 64)];
  split_f16(v, &Xh[i], &Xl[i]);
}

__global__ __launch_bounds__(256) void concat_l1_b(const float* __restrict__ h0,
                                                   const float* __restrict__ h1,
                                                   const float* __restrict__ ZR,
                                                   _Float16* __restrict__ Xh,
                                                   _Float16* __restrict__ Xl) {
  int i = blockIdx.x * 256 + threadIdx.x;
  if (i >= NN * BB * 128) return;
  int c = i & 127;
  int nb = i >> 7;
  float v = (c < 64) ? h0[(size_t)nb * 64 + c]
                     : ZR[(size_t)nb * 128 + (c - 64)] * h1[(size_t)nb * 64 + (c - 64)];
  split_f16(v, &Xh[i], &Xl[i]);
}

// -------- per-node fused weight generation: W[n] = sum_d E[n,d]*wpool[d] -----
// Output layout: Wh/Wl [n][o][KP] f16 (8 consecutive k = one aligned half8).
template <int CIN, int COUT>
__global__ __launch_bounds__(256) void gen_w(const float* __restrict__ E,
                                             const float* __restrict__ wpool,
                                             const float* __restrict__ bpool,
                                             _Float16* __restrict__ Wh,
                                             _Float16* __restrict__ Wl,
                                             float* __restrict__ Bp) {
  constexpr int KD = 2 * CIN;
  constexpr int KP = (KD + 31) & ~31;
  constexpr int NS = 256 / COUT;
  const int n = blockIdx.x;
  const int tid = threadIdx.x;
  __shared__ float sE[EMB];
  if (tid < EMB) sE[tid] = E[n * EMB + tid];
  __syncthreads();
  const int o = tid % COUT;
  const int slot = tid / COUT;
  for (int kp = slot; kp < KP; kp += NS) {
    float w = 0.0f;
    if (kp < KD) {
      const int kk = (kp >= CIN) ? 1 : 0;
      const int ii = kp - kk * CIN;
#pragma unroll
      for (int d = 0; d < EMB; ++d)
        w += sE[d] * wpool[(((size_t)d * 2 + kk) * CIN + ii) * COUT + o];
    }
    _Float16 hh = (_Float16)w;
    Wh[((size_t)n * COUT + o) * KP + kp] = hh;
    Wl[((size_t)n * COUT + o) * KP + kp] = (_Float16)(w - (float)hh);
  }
  if (tid < COUT) {
    float bb = 0.0f;
#pragma unroll
    for (int d = 0; d < EMB; ++d) bb += sE[d] * bpool[d * COUT + tid];
    Bp[n * COUT + tid] = bb;
  }
}

// -------- per-node gconv via MFMA, LDS-free, direct-global fragments ---------
// One block (4 waves) per node. Out tile 64(b) x COUT. K = [x(CIN) ; G(CIN)].
template <int CIN, bool GATE>
__global__ __launch_bounds__(256) void gconv_mfma(
    const _Float16* __restrict__ Xh, const _Float16* __restrict__ Xl,
    const _Float16* __restrict__ Gh, const _Float16* __restrict__ Gl,
    const _Float16* __restrict__ Wh, const _Float16* __restrict__ Wl,
    const float* __restrict__ Bp, const float* __restrict__ ZRc,
    float* __restrict__ outp) {
  constexpr int COUT = GATE ? 128 : 64;
  constexpr int KD = 2 * CIN;
  constexpr int KP = (KD + 31) & ~31;
  constexpr int NT = COUT / 32;  // N-tiles per wave
  const int n = blockIdx.x;
  const int tid = threadIdx.x;
  const int lane = tid & 63, wid = tid >> 6;
  const int wm = (wid & 1) * 32;
  const int wn = (wid >> 1) * (COUT / 2);
  const int l15 = lane & 15, l4 = lane >> 4;
  const size_t xb = (size_t)n * (64 * CIN);
  const _Float16* WhN = Wh + (size_t)n * COUT * KP;
  const _Float16* WlN = Wl + (size_t)n * COUT * KP;

  f32x4 acc[2][NT] = {};

  for (int k0 = 0; k0 < KP; k0 += 32) {
    const int kq = k0 + l4 * 8;  // this lane's 8-k group
    half8 ah[2], al[2];
#pragma unroll
    for (int mt = 0; mt < 2; ++mt) {
      const int b = wm + mt * 16 + l15;
      const size_t off = xb + (size_t)b * CIN;
      if constexpr (CIN % 8 == 0) {  // layer1: aligned vector paths, no pad
        if (kq < CIN) {
          ah[mt] = *(const half8*)&Xh[off + kq];
          al[mt] = *(const half8*)&Xl[off + kq];
        } else {
          ah[mt] = *(const half8*)&Gh[off + kq - CIN];
          al[mt] = *(const half8*)&Gl[off + kq - CIN];
        }
      } else {  // layer0: elementwise with boundary/pad handling
#pragma unroll
        for (int j = 0; j < 8; ++j) {
          const int k = kq + j;
          _Float16 hv = (_Float16)0.f, lv = (_Float16)0.f;
          if (k < CIN) {
            hv = Xh[off + k];
            lv = Xl[off + k];
          } else if (k < KD) {
            hv = Gh[off + k - CIN];
            lv = Gl[off + k - CIN];
          }
          ah[mt][j] = hv;
          al[mt][j] = lv;
        }
      }
    }
#pragma unroll
    for (int nt = 0; nt < NT; ++nt) {
      const int o = wn + nt * 16 + l15;
      const half8 bh = *(const half8*)&WhN[(size_t)o * KP + kq];
      const half8 bl = *(const half8*)&WlN[(size_t)o * KP + kq];
#pragma unroll
      for (int mt = 0; mt < 2; ++mt) {
        acc[mt][nt] =
            __builtin_amdgcn_mfma_f32_16x16x32_f16(ah[mt], bh, acc[mt][nt], 0, 0, 0);
        acc[mt][nt] =
            __builtin_amdgcn_mfma_f32_16x16x32_f16(ah[mt], bl, acc[mt][nt], 0, 0, 0);
        acc[mt][nt] =
            __builtin_amdgcn_mfma_f32_16x16x32_f16(al[mt], bh, acc[mt][nt], 0, 0, 0);
      }
    }
  }
#pragma unroll
  for (int mt = 0; mt < 2; ++mt) {
#pragma unroll
    for (int nt = 0; nt < NT; ++nt) {
      const int o = wn + nt * 16 + l15;
      const float bias = Bp[n * COUT + o];
#pragma unroll
      for (int r = 0; r < 4; ++r) {
        const int b = wm + mt * 16 + l4 * 4 + r;
        const size_t nb = (size_t)n * 64 + b;
        const float v = acc[mt][nt][r] + bias;
        if constexpr (GATE) {
          outp[nb * 128 + o] = 1.0f / (1.0f + expf(-v));
        } else {
          const float hc = tanhf(v);
          const float rr = ZRc[nb * 128 + 64 + o];
          const float hv = outp[nb * 64 + o];
          outp[nb * 64 + o] = rr * hv + (1.0f - rr) * hc;
        }
      }
    }
  }
}

// ---------------- output head ------------------------------------------------
__global__ __launch_bounds__(256) void head_kernel(const float* __restrict__ h1,
                                                   const float* __restrict__ cw,
                                                   const float* __restrict__ cb,
                                                   float* __restrict__ out) {
  int i = blockIdx.x * 256 + threadIdx.x;
  if (i >= BB * NN) return;
  int n = i % NN, b = i / NN;
  const float* hrow = h1 + ((size_t)n * 64 + b) * 64;
  float hv[64];
#pragma unroll
  for (int j = 0; j < 64; ++j) hv[j] = hrow[j];
  for (int o = 0; o < 12; ++o) {
    float s = cb[o];
#pragma unroll
    for (int j = 0; j < 64; ++j) s += hv[j] * cw[o * 64 + j];
    out[((size_t)b * 12 + o) * NN + n] = s;
  }
}

__global__ __launch_bounds__(256) void zero_f32(float* __restrict__ p, int count) {
  int i = blockIdx.x * 256 + threadIdx.x;
  if (i < count) p[i] = 0.0f;
}
__global__ __launch_bounds__(256) void zero_u16(unsigned short* __restrict__ p, int count) {
  int i = blockIdx.x * 256 + threadIdx.x;
  if (i < count) p[i] = 0;
}

extern "C" void kernel_launch(void* const* d_in, const int* in_sizes, int n_in,
                              void* d_out, int out_size, void* d_ws, size_t ws_size,
                              hipStream_t stream) {
  const float* src = (const float*)d_in[0];
  const float* E = (const float*)d_in[1];
  const float* w0g = (const float*)d_in[2];
  const float* b0g = (const float*)d_in[3];
  const float* w0c = (const float*)d_in[4];
  const float* b0c = (const float*)d_in[5];
  const float* w1g = (const float*)d_in[6];
  const float* b1g = (const float*)d_in[7];
  const float* w1c = (const float*)d_in[8];
  const float* b1c = (const float*)d_in[9];
  const float* cw = (const float*)d_in[10];
  const float* cb = (const float*)d_in[11];
  float* out = (float*)d_out;
  float* ws = (float*)d_ws;

  size_t off = 0;
  auto alloc = [&](size_t cnt) {  // cnt in floats
    float* p = ws + off;
    off += (cnt + 63) & ~(size_t)63;
    return p;
  };
  const int L0 = 64 * 65;   // 4160
  const int L1 = 64 * 128;  // 8192
  const int KP0 = 160;      // pad32(2*65)
  const int KP1 = 256;      // 2*128
  _Float16* Ah = (_Float16*)alloc((size_t)KPAD * KPAD / 2);
  _Float16* Al = (_Float16*)alloc((size_t)KPAD * KPAD / 2);
  _Float16* X0h = (_Float16*)alloc((size_t)KPAD * L0 / 2);
  _Float16* X0l = (_Float16*)alloc((size_t)KPAD * L0 / 2);
  _Float16* X1h = (_Float16*)alloc((size_t)KPAD * L1 / 2);
  _Float16* X1l = (_Float16*)alloc((size_t)KPAD * L1 / 2);
  _Float16* Gh = (_Float16*)alloc((size_t)NN * L1 / 2);
  _Float16* Gl = (_Float16*)alloc((size_t)NN * L1 / 2);
  float* ZR = alloc((size_t)NN * BB * 128);
  float* h0 = alloc((size_t)NN * BB * 64);
  float* h1 = alloc((size_t)NN * BB * 64);
  float* Bg0 = alloc((size_t)NN * 128);
  float* Bc0 = alloc((size_t)NN * 64);
  float* Bg1 = alloc((size_t)NN * 128);
  float* Bc1 = alloc((size_t)NN * 64);
  const size_t off_base = off;

  // Full-precompute layout (preferred)
  _Float16* W0gh = (_Float16*)alloc((size_t)NN * 128 * KP0 / 2);
  _Float16* W0gl = (_Float16*)alloc((size_t)NN * 128 * KP0 / 2);
  _Float16* W0ch = (_Float16*)alloc((size_t)NN * 64 * KP0 / 2);
  _Float16* W0cl = (_Float16*)alloc((size_t)NN * 64 * KP0 / 2);
  _Float16* W1gh = (_Float16*)alloc((size_t)NN * 128 * KP1 / 2);
  _Float16* W1gl = (_Float16*)alloc((size_t)NN * 128 * KP1 / 2);
  _Float16* W1ch = (_Float16*)alloc((size_t)NN * 64 * KP1 / 2);
  _Float16* W1cl = (_Float16*)alloc((size_t)NN * 64 * KP1 / 2);
  bool full = (off * sizeof(float) <= ws_size);
  if (!full) {  // fallback: one shared W slot (max set = layer1 gate), regen per call
    off = off_base;
    _Float16* shWh = (_Float16*)alloc((size_t)NN * 128 * KP1 / 2);
    _Float16* shWl = (_Float16*)alloc((size_t)NN * 128 * KP1 / 2);
    if (off * sizeof(float) > ws_size) return;  // can't run: fail loud (zeros)
    W0gh = W0ch = W1gh = W1ch = shWh;
    W0gl = W0cl = W1gl = W1cl = shWl;
  }

  adj_kernel<<<NN, 256, 0, stream>>>(E, Ah, Al);
  int hcount = 2 * NN * BB * 64;  // h0,h1 contiguous
  zero_f32<<<(hcount + 255) / 256, 256, 0, stream>>>(h0, hcount);
  zero_u16<<<(2 * KPAD * L0 + 255) / 256, 256, 0, stream>>>((unsigned short*)X0h,
                                                            2 * KPAD * L0);
  zero_u16<<<(2 * KPAD * L1 + 255) / 256, 256, 0, stream>>>((unsigned short*)X1h,
                                                            2 * KPAD * L1);
  if (full) {
    gen_w<65, 128><<<NN, 256, 0, stream>>>(E, w0g, b0g, W0gh, W0gl, Bg0);
    gen_w<65, 64><<<NN, 256, 0, stream>>>(E, w0c, b0c, W0ch, W0cl, Bc0);
    gen_w<128, 128><<<NN, 256, 0, stream>>>(E, w1g, b1g, W1gh, W1gl, Bg1);
    gen_w<128, 64><<<NN, 256, 0, stream>>>(E, w1c, b1c, W1ch, W1cl, Bc1);
  }

  const int e0 = NN * BB * 65;
  const int e1 = NN * BB * 128;
  const int gx0 = (L0 + 127) / 128;  // 33
  const int gx1 = L1 / 128;          // 64
  for (int t = 0; t < TT; ++t) {
    // ---- layer 0 (x = source[:,t], Cin = 65) ----
    concat_l0_a<<<(e0 + 255) / 256, 256, 0, stream>>>(src, h0, X0h, X0l, t);
    mfma_gemm3<<<dim3(gx0, 7), 256, 0, stream>>>(Ah, Al, X0h, X0l, Gh, Gl, L0);
    if (!full) gen_w<65, 128><<<NN, 256, 0, stream>>>(E, w0g, b0g, W0gh, W0gl, Bg0);
    gconv_mfma<65, true><<<NN, 256, 0, stream>>>(X0h, X0l, Gh, Gl, W0gh, W0gl,
                                                 Bg0, nullptr, ZR);
    concat_l0_b<<<(e0 + 255) / 256, 256, 0, stream>>>(src, h0, ZR, X0h, X0l, t);
    mfma_gemm3<<<dim3(gx0, 7), 256, 0, stream>>>(Ah, Al, X0h, X0l, Gh, Gl, L0);
    if (!full) gen_w<65, 64><<<NN, 256, 0, stream>>>(E, w0c, b0c, W0ch, W0cl, Bc0);
    gconv_mfma<65, false><<<NN, 256, 0, stream>>>(X0h, X0l, Gh, Gl, W0ch, W0cl,
                                                  Bc0, ZR, h0);
    // ---- layer 1 (x = h0 output, Cin = 128) ----
    concat_l1_a<<<(e1 + 255) / 256, 256, 0, stream>>>(h0, h1, X1h, X1l);
    mfma_gemm3<<<dim3(gx1, 7), 256, 0, stream>>>(Ah, Al, X1h, X1l, Gh, Gl, L1);
    if (!full) gen_w<128, 128><<<NN, 256, 0, stream>>>(E, w1g, b1g, W1gh, W1gl, Bg1);
    gconv_mfma<128, true><<<NN, 256, 0, stream>>>(X1h, X1l, Gh, Gl, W1gh, W1gl,
                                                  Bg1, nullptr, ZR);
    concat_l1_b<<<(e1 + 255) / 256, 256, 0, stream>>>(h0, h1, ZR, X1h, X1l);
    mfma_gemm3<<<dim3(gx1, 7), 256, 0, stream>>>(Ah, Al, X1h, X1l, Gh, Gl, L1);
    if (!full) gen_w<128, 64><<<NN, 256, 0, stream>>>(E, w1c, b1c, W1ch, W1cl, Bc1);
    gconv_mfma<128, false><<<NN, 256, 0, stream>>>(X1h, X1l, Gh, Gl, W1ch, W1cl,
                                                   Bc1, ZR, h1);
  }
  head_kernel<<<(BB * NN + 255) / 256, 256, 0, stream>>>(h1, cw, cb, out);
}

// Round 5
// 6653.796 us; speedup vs baseline: 2.2163x; 2.2163x over previous
//
#include <hip/hip_runtime.h>
#include <cstddef>

#define NN 883
#define BB 64
#define TT 12
#define EMB 10
#define KPAD 896  // 883 padded up to multiple of 128 (and of 32)

typedef short short8 __attribute__((ext_vector_type(8)));
typedef _Float16 half8 __attribute__((ext_vector_type(8)));
typedef _Float16 half4 __attribute__((ext_vector_type(4)));
typedef float f32x4 __attribute__((ext_vector_type(4)));

__device__ __forceinline__ void split_f16(float v, _Float16* hp, _Float16* lp) {
  _Float16 h = (_Float16)v;
  *hp = h;
  *lp = (_Float16)(v - (float)h);
}

// -------- adjacency: A = softmax(relu(E E^T), axis=1), emitted as f16 hi/lo --
__global__ __launch_bounds__(256) void adj_kernel(const float* __restrict__ E,
                                                  _Float16* __restrict__ Ah,
                                                  _Float16* __restrict__ Al) {
  const int n = blockIdx.x;
  const int tid = threadIdx.x;
  __shared__ float sE[EMB];
  __shared__ float sred[256];
  if (tid < EMB) sE[tid] = E[n * EMB + tid];
  __syncthreads();
  float d[4];
  float lmax = 0.0f;
#pragma unroll
  for (int q = 0; q < 4; ++q) {
    int m = tid + q * 256;
    d[q] = 0.0f;
    if (m < NN) {
      float s = 0.0f;
#pragma unroll
      for (int e = 0; e < EMB; ++e) s += sE[e] * E[m * EMB + e];
      d[q] = fmaxf(s, 0.0f);
      lmax = fmaxf(lmax, d[q]);
    }
  }
  sred[tid] = lmax;
  __syncthreads();
  for (int s = 128; s > 0; s >>= 1) {
    if (tid < s) sred[tid] = fmaxf(sred[tid], sred[tid + s]);
    __syncthreads();
  }
  const float mx = sred[0];
  __syncthreads();
  float lsum = 0.0f;
#pragma unroll
  for (int q = 0; q < 4; ++q) {
    int m = tid + q * 256;
    if (m < NN) {
      d[q] = expf(d[q] - mx);
      lsum += d[q];
    }
  }
  sred[tid] = lsum;
  __syncthreads();
  for (int s = 128; s > 0; s >>= 1) {
    if (tid < s) sred[tid] += sred[tid + s];
    __syncthreads();
  }
  const float inv = 1.0f / sred[0];
#pragma unroll
  for (int q = 0; q < 4; ++q) {
    int m = tid + q * 256;
    if (m < KPAD) {
      float v = (m < NN) ? d[q] * inv : 0.0f;
      split_f16(v, &Ah[(size_t)n * KPAD + m], &Al[(size_t)n * KPAD + m]);
    }
  }
}

// -------- 3-term split-f16 MFMA GEMM; output written as split f16 (Gh/Gl) ----
// 128x128 block tile, 4 waves 2x2, each wave 64x64 via 4x4 MFMA 16x16x32.
__global__ __launch_bounds__(256) void mfma_gemm3(const _Float16* __restrict__ Ah,
                                                  const _Float16* __restrict__ Al,
                                                  const _Float16* __restrict__ Xh,
                                                  const _Float16* __restrict__ Xl,
                                                  _Float16* __restrict__ Gh,
                                                  _Float16* __restrict__ Gl, int L) {
  __shared__ _Float16 sA[2][128][40];    // [hi/lo][m][k], pad 32->40
  __shared__ _Float16 sX[2][4][128][8];  // [hi/lo][k-octet][l][k&7]
  const int tid = threadIdx.x;
  const int lane = tid & 63;
  const int wid = tid >> 6;
  const int wm = (wid >> 1) * 64, wn = (wid & 1) * 64;
  const int bm = blockIdx.y * 128;
  const int bl = blockIdx.x * 128;
  const int l15 = lane & 15, l4 = lane >> 4;

  f32x4 acc[4][4] = {};

  const int xlp = (tid & 63) * 2;  // l-pair this thread stages
  const int xko = tid >> 6;        // k-octet this thread stages

  for (int k0 = 0; k0 < KPAD; k0 += 32) {
    __syncthreads();
#pragma unroll
    for (int p = 0; p < 2; ++p) {
      int i = tid + p * 256;
      int m = i >> 2, k8 = (i & 3) * 8;
      *(half8*)&sA[0][m][k8] = *(const half8*)&Ah[(size_t)(bm + m) * KPAD + k0 + k8];
      *(half8*)&sA[1][m][k8] = *(const half8*)&Al[(size_t)(bm + m) * KPAD + k0 + k8];
    }
    {
      int gl = bl + xlp;
      int kb = k0 + xko * 8;
#pragma unroll
      for (int buf = 0; buf < 2; ++buf) {
        const _Float16* Xp = buf ? Xl : Xh;
        unsigned int v[8];
        if (gl < L) {
#pragma unroll
          for (int j = 0; j < 8; ++j)
            v[j] = *(const unsigned int*)&Xp[(size_t)(kb + j) * L + gl];
        } else {
#pragma unroll
          for (int j = 0; j < 8; ++j) v[j] = 0u;
        }
        short8 lo, hi;
#pragma unroll
        for (int j = 0; j < 8; ++j) {
          lo[j] = (short)(v[j] & 0xFFFFu);
          hi[j] = (short)(v[j] >> 16);
        }
        *(short8*)&sX[buf][xko][xlp][0] = lo;
        *(short8*)&sX[buf][xko][xlp + 1][0] = hi;
      }
    }
    __syncthreads();
    half8 afh[4], afl[4], bfh[4], bfl[4];
#pragma unroll
    for (int mi = 0; mi < 4; ++mi) {
      afh[mi] = *(half8*)&sA[0][wm + mi * 16 + l15][l4 * 8];
      afl[mi] = *(half8*)&sA[1][wm + mi * 16 + l15][l4 * 8];
    }
#pragma unroll
    for (int ni = 0; ni < 4; ++ni) {
      bfh[ni] = *(half8*)&sX[0][l4][wn + ni * 16 + l15][0];
      bfl[ni] = *(half8*)&sX[1][l4][wn + ni * 16 + l15][0];
    }
#pragma unroll
    for (int mi = 0; mi < 4; ++mi)
#pragma unroll
      for (int ni = 0; ni < 4; ++ni) {
        acc[mi][ni] = __builtin_amdgcn_mfma_f32_16x16x32_f16(afh[mi], bfh[ni],
                                                             acc[mi][ni], 0, 0, 0);
        acc[mi][ni] = __builtin_amdgcn_mfma_f32_16x16x32_f16(afh[mi], bfl[ni],
                                                             acc[mi][ni], 0, 0, 0);
        acc[mi][ni] = __builtin_amdgcn_mfma_f32_16x16x32_f16(afl[mi], bfh[ni],
                                                             acc[mi][ni], 0, 0, 0);
      }
  }
#pragma unroll
  for (int mi = 0; mi < 4; ++mi) {
    int row0 = bm + wm + mi * 16 + l4 * 4;
#pragma unroll
    for (int ni = 0; ni < 4; ++ni) {
      int col = bl + wn + ni * 16 + l15;
      if (col < L) {
#pragma unroll
        for (int r = 0; r < 4; ++r) {
          int row = row0 + r;
          if (row < NN)
            split_f16(acc[mi][ni][r], &Gh[(size_t)row * L + col],
                      &Gl[(size_t)row * L + col]);
        }
      }
    }
  }
}

// ---------------- concat builders (node-major [n][b][c], f16 hi/lo out) ------
__global__ __launch_bounds__(256) void concat_l0_a(const float* __restrict__ src,
                                                   const float* __restrict__ h0,
                                                   _Float16* __restrict__ Xh,
                                                   _Float16* __restrict__ Xl, int t) {
  int i = blockIdx.x * 256 + threadIdx.x;
  if (i >= NN * BB * 65) return;
  int c = i % 65;
  int nb = i / 65;
  int b = nb & 63;
  int n = nb >> 6;
  float v = (c == 0) ? src[((size_t)b * TT + t) * NN + n]
                     : h0[(size_t)nb * 64 + (c - 1)];
  split_f16(v, &Xh[i], &Xl[i]);
}

__global__ __launch_bounds__(256) void concat_l0_b(const float* __restrict__ src,
                                                   const float* __restrict__ h0,
                                                   const float* __restrict__ ZR,
                                                   _Float16* __restrict__ Xh,
                                                   _Float16* __restrict__ Xl, int t) {
  int i = blockIdx.x * 256 + threadIdx.x;
  if (i >= NN * BB * 65) return;
  int c = i % 65;
  int nb = i / 65;
  int b = nb & 63;
  int n = nb >> 6;
  float v = (c == 0) ? src[((size_t)b * TT + t) * NN + n]
                     : ZR[(size_t)nb * 128 + (c - 1)] * h0[(size_t)nb * 64 + (c - 1)];
  split_f16(v, &Xh[i], &Xl[i]);
}

__global__ __launch_bounds__(256) void concat_l1_a(const float* __restrict__ h0,
                                                   const float* __restrict__ h1,
                                                   _Float16* __restrict__ Xh,
                                                   _Float16* __restrict__ Xl) {
  int i = blockIdx.x * 256 + threadIdx.x;
  if (i >= NN * BB * 128) return;
  int c = i & 127;
  int nb = i >> 7;
  float v = (c < 64) ? h0[(size_t)nb * 64 + c] : h1[(size_t)nb * 64 + (c - 64)];
  split_f16(v, &Xh[i], &Xl[i]);
}

__global__ __launch_bounds__(256) void concat_l1_b(const float* __restrict__ h0,
                                                   const float* __restrict__ h1,
                                                   const float* __restrict__ ZR,
                                                   _Float16* __restrict__ Xh,
                                                   _Float16* __restrict__ Xl) {
  int i = blockIdx.x * 256 + threadIdx.x;
  if (i >= NN * BB * 128) return;
  int c = i & 127;
  int nb = i >> 7;
  float v = (c < 64) ? h0[(size_t)nb * 64 + c]
                     : ZR[(size_t)nb * 128 + (c - 64)] * h1[(size_t)nb * 64 + (c - 64)];
  split_f16(v, &Xh[i], &Xl[i]);
}

// -------- fused per-node gconv: W generated in LDS, MFMA contraction ---------
// grid = (NN, COUT/64). Block: 64 b-rows x 64 o-cols; W chunk [64 o][KP] hi/lo.
template <int CIN, bool GATE>
__global__ __launch_bounds__(256) void gconv_fused(
    const _Float16* __restrict__ Xh, const _Float16* __restrict__ Xl,
    const _Float16* __restrict__ Gh, const _Float16* __restrict__ Gl,
    const float* __restrict__ E, const float* __restrict__ wpool,
    const float* __restrict__ bpool, const float* __restrict__ ZRc,
    float* __restrict__ outp) {
  constexpr int COUT = GATE ? 128 : 64;
  constexpr int KD = 2 * CIN;
  constexpr int KP = (KD + 31) & ~31;  // 160 (CIN=65) / 256 (CIN=128)
  constexpr int RS = KP + 8;           // LDS row stride: keeps 16B align, spreads banks
  const int n = blockIdx.x;
  const int och = blockIdx.y * 64;
  const int tid = threadIdx.x;
  const int lane = tid & 63, wid = tid >> 6;
  const int wm = (wid & 1) * 32;
  const int wn = (wid >> 1) * 32;
  const int l15 = lane & 15, l4 = lane >> 4;

  __shared__ float sE[EMB];
  __shared__ float sB[64];
  __shared__ _Float16 sWh[64 * RS];
  __shared__ _Float16 sWl[64 * RS];

  if (tid < EMB) sE[tid] = E[n * EMB + tid];
  __syncthreads();

  // ---- generate W chunk: W[o][k] = sum_d E[n,d] * wpool[d,k,och+o] ----
  {
    const int o = tid & 63;          // consecutive lanes -> consecutive o (coalesced)
    const int kp0 = (tid >> 6) * 4;  // 4 consecutive kp per thread per iter
    for (int kp = kp0; kp < KP; kp += 16) {
      half4 hv, lv;
#pragma unroll
      for (int j = 0; j < 4; ++j) {
        const int k = kp + j;
        float w = 0.0f;
        if (k < KD) {
          const int kk = (k >= CIN) ? 1 : 0;
          const int ii = k - kk * CIN;
          const float* wp = wpool + ((size_t)kk * CIN + ii) * COUT + och + o;
#pragma unroll
          for (int d = 0; d < EMB; ++d)
            w += sE[d] * wp[(size_t)d * (2 * CIN * COUT)];
        }
        _Float16 hh = (_Float16)w;
        hv[j] = hh;
        lv[j] = (_Float16)(w - (float)hh);
      }
      *(half4*)&sWh[o * RS + kp] = hv;
      *(half4*)&sWl[o * RS + kp] = lv;
    }
    if (tid < 64) {
      float bb = 0.0f;
#pragma unroll
      for (int d = 0; d < EMB; ++d) bb += sE[d] * bpool[d * COUT + och + tid];
      sB[tid] = bb;
    }
  }
  __syncthreads();

  // ---- MFMA contraction: A (xg) direct from global, B (W) from LDS ----
  const size_t xb = (size_t)n * (64 * CIN);
  f32x4 acc[2][2] = {};
  for (int k0 = 0; k0 < KP; k0 += 32) {
    const int kq = k0 + l4 * 8;  // this lane's 8-k group
    half8 ah[2], al[2];
#pragma unroll
    for (int mt = 0; mt < 2; ++mt) {
      const int b = wm + mt * 16 + l15;
      const size_t off = xb + (size_t)b * CIN;
      if constexpr (CIN % 8 == 0) {  // layer1: aligned vector path, KP == KD
        if (kq < CIN) {
          ah[mt] = *(const half8*)&Xh[off + kq];
          al[mt] = *(const half8*)&Xl[off + kq];
        } else {
          ah[mt] = *(const half8*)&Gh[off + kq - CIN];
          al[mt] = *(const half8*)&Gl[off + kq - CIN];
        }
      } else {  // layer0: elementwise with boundary/pad handling
#pragma unroll
        for (int j = 0; j < 8; ++j) {
          const int k = kq + j;
          _Float16 hv = (_Float16)0.f, lv = (_Float16)0.f;
          if (k < CIN) {
            hv = Xh[off + k];
            lv = Xl[off + k];
          } else if (k < KD) {
            hv = Gh[off + k - CIN];
            lv = Gl[off + k - CIN];
          }
          ah[mt][j] = hv;
          al[mt][j] = lv;
        }
      }
    }
#pragma unroll
    for (int nt = 0; nt < 2; ++nt) {
      const int ol = wn + nt * 16 + l15;
      const half8 bh = *(const half8*)&sWh[ol * RS + kq];
      const half8 bl = *(const half8*)&sWl[ol * RS + kq];
#pragma unroll
      for (int mt = 0; mt < 2; ++mt) {
        acc[mt][nt] =
            __builtin_amdgcn_mfma_f32_16x16x32_f16(ah[mt], bh, acc[mt][nt], 0, 0, 0);
        acc[mt][nt] =
            __builtin_amdgcn_mfma_f32_16x16x32_f16(ah[mt], bl, acc[mt][nt], 0, 0, 0);
        acc[mt][nt] =
            __builtin_amdgcn_mfma_f32_16x16x32_f16(al[mt], bh, acc[mt][nt], 0, 0, 0);
      }
    }
  }

  // ---- epilogue ----
#pragma unroll
  for (int mt = 0; mt < 2; ++mt) {
#pragma unroll
    for (int nt = 0; nt < 2; ++nt) {
      const int ol = wn + nt * 16 + l15;
      const int o = och + ol;
      const float bias = sB[ol];
#pragma unroll
      for (int r = 0; r < 4; ++r) {
        const int b = wm + mt * 16 + l4 * 4 + r;
        const size_t nb = (size_t)n * 64 + b;
        const float v = acc[mt][nt][r] + bias;
        if constexpr (GATE) {
          outp[nb * 128 + o] = 1.0f / (1.0f + expf(-v));
        } else {
          const float hc = tanhf(v);
          const float rr = ZRc[nb * 128 + 64 + o];
          const float hv = outp[nb * 64 + o];
          outp[nb * 64 + o] = rr * hv + (1.0f - rr) * hc;
        }
      }
    }
  }
}

// ---------------- output head ------------------------------------------------
__global__ __launch_bounds__(256) void head_kernel(const float* __restrict__ h1,
                                                   const float* __restrict__ cw,
                                                   const float* __restrict__ cb,
                                                   float* __restrict__ out) {
  int i = blockIdx.x * 256 + threadIdx.x;
  if (i >= BB * NN) return;
  int n = i % NN, b = i / NN;
  const float* hrow = h1 + ((size_t)n * 64 + b) * 64;
  float hv[64];
#pragma unroll
  for (int j = 0; j < 64; ++j) hv[j] = hrow[j];
  for (int o = 0; o < 12; ++o) {
    float s = cb[o];
#pragma unroll
    for (int j = 0; j < 64; ++j) s += hv[j] * cw[o * 64 + j];
    out[((size_t)b * 12 + o) * NN + n] = s;
  }
}

__global__ __launch_bounds__(256) void zero_f32(float* __restrict__ p, int count) {
  int i = blockIdx.x * 256 + threadIdx.x;
  if (i < count) p[i] = 0.0f;
}
__global__ __launch_bounds__(256) void zero_u16(unsigned short* __restrict__ p, int count) {
  int i = blockIdx.x * 256 + threadIdx.x;
  if (i < count) p[i] = 0;
}

extern "C" void kernel_launch(void* const* d_in, const int* in_sizes, int n_in,
                              void* d_out, int out_size, void* d_ws, size_t ws_size,
                              hipStream_t stream) {
  const float* src = (const float*)d_in[0];
  const float* E = (const float*)d_in[1];
  const float* w0g = (const float*)d_in[2];
  const float* b0g = (const float*)d_in[3];
  const float* w0c = (const float*)d_in[4];
  const float* b0c = (const float*)d_in[5];
  const float* w1g = (const float*)d_in[6];
  const float* b1g = (const float*)d_in[7];
  const float* w1c = (const float*)d_in[8];
  const float* b1c = (const float*)d_in[9];
  const float* cw = (const float*)d_in[10];
  const float* cb = (const float*)d_in[11];
  float* out = (float*)d_out;
  float* ws = (float*)d_ws;

  size_t off = 0;
  auto alloc = [&](size_t cnt) {  // cnt in floats
    float* p = ws + off;
    off += (cnt + 63) & ~(size_t)63;
    return p;
  };
  const int L0 = 64 * 65;   // 4160
  const int L1 = 64 * 128;  // 8192
  _Float16* Ah = (_Float16*)alloc((size_t)KPAD * KPAD / 2);
  _Float16* Al = (_Float16*)alloc((size_t)KPAD * KPAD / 2);
  _Float16* X0h = (_Float16*)alloc((size_t)KPAD * L0 / 2);
  _Float16* X0l = (_Float16*)alloc((size_t)KPAD * L0 / 2);
  _Float16* X1h = (_Float16*)alloc((size_t)KPAD * L1 / 2);
  _Float16* X1l = (_Float16*)alloc((size_t)KPAD * L1 / 2);
  _Float16* Gh = (_Float16*)alloc((size_t)NN * L1 / 2);
  _Float16* Gl = (_Float16*)alloc((size_t)NN * L1 / 2);
  float* ZR = alloc((size_t)NN * BB * 128);
  float* h0 = alloc((size_t)NN * BB * 64);
  float* h1 = alloc((size_t)NN * BB * 64);
  if (off * sizeof(float) > ws_size) return;  // ws too small: fail loud (zeros)

  adj_kernel<<<NN, 256, 0, stream>>>(E, Ah, Al);
  int hcount = 2 * NN * BB * 64;  // h0,h1 contiguous
  zero_f32<<<(hcount + 255) / 256, 256, 0, stream>>>(h0, hcount);
  zero_u16<<<(2 * KPAD * L0 + 255) / 256, 256, 0, stream>>>((unsigned short*)X0h,
                                                            2 * KPAD * L0);
  zero_u16<<<(2 * KPAD * L1 + 255) / 256, 256, 0, stream>>>((unsigned short*)X1h,
                                                            2 * KPAD * L1);

  const int e0 = NN * BB * 65;
  const int e1 = NN * BB * 128;
  const int gx0 = (L0 + 127) / 128;  // 33
  const int gx1 = L1 / 128;          // 64
  for (int t = 0; t < TT; ++t) {
    // ---- layer 0 (x = source[:,t], Cin = 65) ----
    concat_l0_a<<<(e0 + 255) / 256, 256, 0, stream>>>(src, h0, X0h, X0l, t);
    mfma_gemm3<<<dim3(gx0, 7), 256, 0, stream>>>(Ah, Al, X0h, X0l, Gh, Gl, L0);
    gconv_fused<65, true><<<dim3(NN, 2), 256, 0, stream>>>(X0h, X0l, Gh, Gl, E,
                                                           w0g, b0g, nullptr, ZR);
    concat_l0_b<<<(e0 + 255) / 256, 256, 0, stream>>>(src, h0, ZR, X0h, X0l, t);
    mfma_gemm3<<<dim3(gx0, 7), 256, 0, stream>>>(Ah, Al, X0h, X0l, Gh, Gl, L0);
    gconv_fused<65, false><<<dim3(NN, 1), 256, 0, stream>>>(X0h, X0l, Gh, Gl, E,
                                                            w0c, b0c, ZR, h0);
    // ---- layer 1 (x = h0 output, Cin = 128) ----
    concat_l1_a<<<(e1 + 255) / 256, 256, 0, stream>>>(h0, h1, X1h, X1l);
    mfma_gemm3<<<dim3(gx1, 7), 256, 0, stream>>>(Ah, Al, X1h, X1l, Gh, Gl, L1);
    gconv_fused<128, true><<<dim3(NN, 2), 256, 0, stream>>>(X1h, X1l, Gh, Gl, E,
                                                            w1g, b1g, nullptr, ZR);
    concat_l1_b<<<(e1 + 255) / 256, 256, 0, stream>>>(h0, h1, ZR, X1h, X1l);
    mfma_gemm3<<<dim3(gx1, 7), 256, 0, stream>>>(Ah, Al, X1h, X1l, Gh, Gl, L1);
    gconv_fused<128, false><<<dim3(NN, 1), 256, 0, stream>>>(X1h, X1l, Gh, Gl, E,
                                                             w1c, b1c, ZR, h1);
  }
  head_kernel<<<(BB * NN + 255) / 256, 256, 0, stream>>>(h1, cw, cb, out);
}

// Round 6
// 5353.759 us; speedup vs baseline: 2.7544x; 1.2428x over previous
//
#include <hip/hip_runtime.h>
#include <cstddef>

#define NN 883
#define BB 64
#define TT 12
#define EMB 10
#define KPAD 896  // node dim padded to multiple of 128

typedef short short8 __attribute__((ext_vector_type(8)));
typedef _Float16 half8 __attribute__((ext_vector_type(8)));
typedef float f32x4 __attribute__((ext_vector_type(4)));

__device__ __forceinline__ void split_f16(float v, _Float16* hp, _Float16* lp) {
  _Float16 h = (_Float16)v;
  *hp = h;
  *lp = (_Float16)(v - (float)h);
}

// -------- adjacency: A = softmax(relu(E E^T), axis=1), emitted as f16 hi/lo --
__global__ __launch_bounds__(256) void adj_kernel(const float* __restrict__ E,
                                                  _Float16* __restrict__ Ah,
                                                  _Float16* __restrict__ Al) {
  const int n = blockIdx.x;
  const int tid = threadIdx.x;
  __shared__ float sE[EMB];
  __shared__ float sred[256];
  if (tid < EMB) sE[tid] = E[n * EMB + tid];
  __syncthreads();
  float d[4];
  float lmax = 0.0f;
#pragma unroll
  for (int q = 0; q < 4; ++q) {
    int m = tid + q * 256;
    d[q] = 0.0f;
    if (m < NN) {
      float s = 0.0f;
#pragma unroll
      for (int e = 0; e < EMB; ++e) s += sE[e] * E[m * EMB + e];
      d[q] = fmaxf(s, 0.0f);
      lmax = fmaxf(lmax, d[q]);
    }
  }
  sred[tid] = lmax;
  __syncthreads();
  for (int s = 128; s > 0; s >>= 1) {
    if (tid < s) sred[tid] = fmaxf(sred[tid], sred[tid + s]);
    __syncthreads();
  }
  const float mx = sred[0];
  __syncthreads();
  float lsum = 0.0f;
#pragma unroll
  for (int q = 0; q < 4; ++q) {
    int m = tid + q * 256;
    if (m < NN) {
      d[q] = expf(d[q] - mx);
      lsum += d[q];
    }
  }
  sred[tid] = lsum;
  __syncthreads();
  for (int s = 128; s > 0; s >>= 1) {
    if (tid < s) sred[tid] += sred[tid + s];
    __syncthreads();
  }
  const float inv = 1.0f / sred[0];
#pragma unroll
  for (int q = 0; q < 4; ++q) {
    int m = tid + q * 256;
    if (m < KPAD) {
      float v = (m < NN) ? d[q] * inv : 0.0f;
      split_f16(v, &Ah[(size_t)n * KPAD + m], &Al[(size_t)n * KPAD + m]);
    }
  }
}

// -------- 3-term split-f16 MFMA GEMM; output written as split f16 (Gh/Gl) ----
__global__ __launch_bounds__(256) void mfma_gemm3(const _Float16* __restrict__ Ah,
                                                  const _Float16* __restrict__ Al,
                                                  const _Float16* __restrict__ Xh,
                                                  const _Float16* __restrict__ Xl,
                                                  _Float16* __restrict__ Gh,
                                                  _Float16* __restrict__ Gl, int L) {
  __shared__ _Float16 sA[2][128][40];
  __shared__ _Float16 sX[2][4][128][8];
  const int tid = threadIdx.x;
  const int lane = tid & 63;
  const int wid = tid >> 6;
  const int wm = (wid >> 1) * 64, wn = (wid & 1) * 64;
  const int bm = blockIdx.y * 128;
  const int bl = blockIdx.x * 128;
  const int l15 = lane & 15, l4 = lane >> 4;

  f32x4 acc[4][4] = {};

  const int xlp = (tid & 63) * 2;
  const int xko = tid >> 6;

  for (int k0 = 0; k0 < KPAD; k0 += 32) {
    __syncthreads();
#pragma unroll
    for (int p = 0; p < 2; ++p) {
      int i = tid + p * 256;
      int m = i >> 2, k8 = (i & 3) * 8;
      *(half8*)&sA[0][m][k8] = *(const half8*)&Ah[(size_t)(bm + m) * KPAD + k0 + k8];
      *(half8*)&sA[1][m][k8] = *(const half8*)&Al[(size_t)(bm + m) * KPAD + k0 + k8];
    }
    {
      int gl = bl + xlp;
      int kb = k0 + xko * 8;
#pragma unroll
      for (int buf = 0; buf < 2; ++buf) {
        const _Float16* Xp = buf ? Xl : Xh;
        unsigned int v[8];
#pragma unroll
        for (int j = 0; j < 8; ++j)
          v[j] = *(const unsigned int*)&Xp[(size_t)(kb + j) * L + gl];
        short8 lo, hi;
#pragma unroll
        for (int j = 0; j < 8; ++j) {
          lo[j] = (short)(v[j] & 0xFFFFu);
          hi[j] = (short)(v[j] >> 16);
        }
        *(short8*)&sX[buf][xko][xlp][0] = lo;
        *(short8*)&sX[buf][xko][xlp + 1][0] = hi;
      }
    }
    __syncthreads();
    half8 afh[4], afl[4], bfh[4], bfl[4];
#pragma unroll
    for (int mi = 0; mi < 4; ++mi) {
      afh[mi] = *(half8*)&sA[0][wm + mi * 16 + l15][l4 * 8];
      afl[mi] = *(half8*)&sA[1][wm + mi * 16 + l15][l4 * 8];
    }
#pragma unroll
    for (int ni = 0; ni < 4; ++ni) {
      bfh[ni] = *(half8*)&sX[0][l4][wn + ni * 16 + l15][0];
      bfl[ni] = *(half8*)&sX[1][l4][wn + ni * 16 + l15][0];
    }
#pragma unroll
    for (int mi = 0; mi < 4; ++mi)
#pragma unroll
      for (int ni = 0; ni < 4; ++ni) {
        acc[mi][ni] = __builtin_amdgcn_mfma_f32_16x16x32_f16(afh[mi], bfh[ni],
                                                             acc[mi][ni], 0, 0, 0);
        acc[mi][ni] = __builtin_amdgcn_mfma_f32_16x16x32_f16(afh[mi], bfl[ni],
                                                             acc[mi][ni], 0, 0, 0);
        acc[mi][ni] = __builtin_amdgcn_mfma_f32_16x16x32_f16(afl[mi], bfh[ni],
                                                             acc[mi][ni], 0, 0, 0);
      }
  }
#pragma unroll
  for (int mi = 0; mi < 4; ++mi) {
    int row0 = bm + wm + mi * 16 + l4 * 4;
#pragma unroll
    for (int ni = 0; ni < 4; ++ni) {
      int col = bl + wn + ni * 16 + l15;
#pragma unroll
      for (int r = 0; r < 4; ++r) {
        int row = row0 + r;
        if (row < NN)
          split_f16(acc[mi][ni][r], &Gh[(size_t)row * L + col],
                    &Gl[(size_t)row * L + col]);
      }
    }
  }
}

// -------- per-step x injection: write src[:,t] into c=0 of X0a and X0b -------
__global__ __launch_bounds__(256) void src_kernel(const float* __restrict__ src,
                                                  _Float16* __restrict__ Xah,
                                                  _Float16* __restrict__ Xal,
                                                  _Float16* __restrict__ Xbh,
                                                  _Float16* __restrict__ Xbl, int t) {
  int i = blockIdx.x * 256 + threadIdx.x;
  if (i >= NN * BB) return;
  int b = i & 63, n = i >> 6;
  float v = src[((size_t)b * TT + t) * NN + n];
  size_t idx = (size_t)n * (64 * 72) + (size_t)b * 72;
  _Float16 hh = (_Float16)v;
  _Float16 ll = (_Float16)(v - (float)hh);
  Xah[idx] = hh;
  Xal[idx] = ll;
  Xbh[idx] = hh;
  Xbl[idx] = ll;
}

// -------- fused per-node gconv: W gen in LDS (octet layout) + MFMA -----------
// CS: channel stride (72 l0 / 128 l1); CIN: real x-channels (65 / 128).
// GATE: COUT=128, grid (NN,2); y=0 -> z-half (writes z*h into XA), y=1 -> r
// (writes ZRout). !GATE: COUT=64, grid (NN,1); GRU update, writes h-state f32
// and split-f16 copies into XA/XB/XC (next GEMM inputs).
template <int CS, int CIN, bool GATE>
__global__ __launch_bounds__(256) void gconv_fused(
    const _Float16* __restrict__ Xh, const _Float16* __restrict__ Xl,
    const _Float16* __restrict__ Gh, const _Float16* __restrict__ Gl,
    const float* __restrict__ E, const float* __restrict__ wpool,
    const float* __restrict__ bpool, const float* __restrict__ ZRin,
    float* __restrict__ hstate, float* __restrict__ ZRout,
    _Float16* __restrict__ XAh, _Float16* __restrict__ XAl, int csA, int cbA,
    _Float16* __restrict__ XBh, _Float16* __restrict__ XBl, int csB, int cbB,
    _Float16* __restrict__ XCh, _Float16* __restrict__ XCl, int csC, int cbC) {
  constexpr int COUT = GATE ? 128 : 64;
  constexpr int KD = 2 * CS;
  constexpr int KP = (KD + 31) & ~31;  // 160 / 256
  constexpr int KO = KP / 8;
  const int n = blockIdx.x;
  const int och = GATE ? (blockIdx.y * 64) : 0;
  const int tid = threadIdx.x;
  const int lane = tid & 63, wid = tid >> 6;
  const int wm = (wid & 1) * 32;
  const int wn = (wid >> 1) * 32;
  const int l15 = lane & 15, l4 = lane >> 4;

  __shared__ float sE[EMB];
  __shared__ float sB[64];
  __shared__ _Float16 sWh[KO * 64 * 8];
  __shared__ _Float16 sWl[KO * 64 * 8];

  if (tid < EMB) sE[tid] = E[n * EMB + tid];
  __syncthreads();

  // ---- W gen: octet layout sW[ko][o][8]; coalesced wpool reads & LDS writes --
  {
    const int o = tid & 63;
    for (int ko = tid >> 6; ko < KO; ko += 4) {
      half8 hv, lv;
#pragma unroll
      for (int j = 0; j < 8; ++j) {
        const int k = ko * 8 + j;
        const int kk = (k >= CS) ? 1 : 0;
        const int ii = k - kk * CS;
        float w = 0.0f;
        if ((CIN == CS) || (k < KD && ii < CIN)) {
          const float* wp = wpool + ((size_t)kk * CIN + ii) * COUT + och + o;
#pragma unroll
          for (int d = 0; d < EMB; ++d)
            w += sE[d] * wp[(size_t)d * (2 * CIN * COUT)];
        }
        _Float16 hh = (_Float16)w;
        hv[j] = hh;
        lv[j] = (_Float16)(w - (float)hh);
      }
      *(half8*)&sWh[((size_t)ko * 64 + o) * 8] = hv;
      *(half8*)&sWl[((size_t)ko * 64 + o) * 8] = lv;
    }
    if (tid < 64) {
      float bb = 0.0f;
#pragma unroll
      for (int d = 0; d < EMB; ++d) bb += sE[d] * bpool[d * COUT + och + tid];
      sB[tid] = bb;
    }
  }
  __syncthreads();

  // ---- MFMA: A (xg) aligned half8 direct from global, B (W) from LDS --------
  const size_t xb = (size_t)n * (64 * CS);
  f32x4 acc[2][2] = {};
  for (int k0 = 0; k0 < KP; k0 += 32) {
    const int kq = k0 + l4 * 8;
    half8 ah[2], al[2];
#pragma unroll
    for (int mt = 0; mt < 2; ++mt) {
      const int b = wm + mt * 16 + l15;
      const size_t off = xb + (size_t)b * CS;
      if (kq < CS) {
        ah[mt] = *(const half8*)&Xh[off + kq];
        al[mt] = *(const half8*)&Xl[off + kq];
      } else if (kq < KD) {
        ah[mt] = *(const half8*)&Gh[off + kq - CS];
        al[mt] = *(const half8*)&Gl[off + kq - CS];
      } else {
        ah[mt] = (half8)(_Float16)0.f;
        al[mt] = (half8)(_Float16)0.f;
      }
    }
    const int koi = kq >> 3;
#pragma unroll
    for (int nt = 0; nt < 2; ++nt) {
      const int ol = wn + nt * 16 + l15;
      const half8 bh = *(const half8*)&sWh[((size_t)koi * 64 + ol) * 8];
      const half8 bl = *(const half8*)&sWl[((size_t)koi * 64 + ol) * 8];
#pragma unroll
      for (int mt = 0; mt < 2; ++mt) {
        acc[mt][nt] =
            __builtin_amdgcn_mfma_f32_16x16x32_f16(ah[mt], bh, acc[mt][nt], 0, 0, 0);
        acc[mt][nt] =
            __builtin_amdgcn_mfma_f32_16x16x32_f16(ah[mt], bl, acc[mt][nt], 0, 0, 0);
        acc[mt][nt] =
            __builtin_amdgcn_mfma_f32_16x16x32_f16(al[mt], bh, acc[mt][nt], 0, 0, 0);
      }
    }
  }

  // ---- epilogue ----
#pragma unroll
  for (int mt = 0; mt < 2; ++mt) {
#pragma unroll
    for (int nt = 0; nt < 2; ++nt) {
      const int ol = wn + nt * 16 + l15;
      const float bias = sB[ol];
#pragma unroll
      for (int r = 0; r < 4; ++r) {
        const int b = wm + mt * 16 + l4 * 4 + r;
        const size_t nb = (size_t)n * 64 + b;
        const float v = acc[mt][nt][r] + bias;
        if constexpr (GATE) {
          const float s = 1.0f / (1.0f + expf(-v));
          if (blockIdx.y == 0) {  // z half: write z*h into cand GEMM input
            const float zh = s * hstate[nb * 64 + ol];
            split_f16(zh, &XAh[(size_t)n * 64 * csA + (size_t)b * csA + cbA + ol],
                      &XAl[(size_t)n * 64 * csA + (size_t)b * csA + cbA + ol]);
          } else {  // r half
            ZRout[nb * 64 + ol] = s;
          }
        } else {
          const float hc = tanhf(v);
          const float rr = ZRin[nb * 64 + ol];
          const float hold = hstate[nb * 64 + ol];
          const float hn = rr * hold + (1.0f - rr) * hc;
          hstate[nb * 64 + ol] = hn;
          _Float16 hh = (_Float16)hn;
          _Float16 ll = (_Float16)(hn - (float)hh);
          size_t ia = (size_t)n * 64 * csA + (size_t)b * csA + cbA + ol;
          XAh[ia] = hh;
          XAl[ia] = ll;
          if (XBh) {
            size_t ib = (size_t)n * 64 * csB + (size_t)b * csB + cbB + ol;
            XBh[ib] = hh;
            XBl[ib] = ll;
          }
          if (XCh) {
            size_t ic = (size_t)n * 64 * csC + (size_t)b * csC + cbC + ol;
            XCh[ic] = hh;
            XCl[ic] = ll;
          }
        }
      }
    }
  }
}

// ---------------- output head ------------------------------------------------
__global__ __launch_bounds__(256) void head_kernel(const float* __restrict__ h1,
                                                   const float* __restrict__ cw,
                                                   const float* __restrict__ cb,
                                                   float* __restrict__ out) {
  int i = blockIdx.x * 256 + threadIdx.x;
  if (i >= BB * NN) return;
  int n = i % NN, b = i / NN;
  const float* hrow = h1 + ((size_t)n * 64 + b) * 64;
  float hv[64];
#pragma unroll
  for (int j = 0; j < 64; ++j) hv[j] = hrow[j];
  for (int o = 0; o < 12; ++o) {
    float s = cb[o];
#pragma unroll
    for (int j = 0; j < 64; ++j) s += hv[j] * cw[o * 64 + j];
    out[((size_t)b * 12 + o) * NN + n] = s;
  }
}

__global__ __launch_bounds__(256) void zero_f32(float* __restrict__ p, size_t count) {
  size_t i = (size_t)blockIdx.x * 256 + threadIdx.x;
  if (i < count) p[i] = 0.0f;
}
__global__ __launch_bounds__(256) void zero_u16(unsigned short* __restrict__ p,
                                                size_t count) {
  size_t i = (size_t)blockIdx.x * 256 + threadIdx.x;
  if (i < count) p[i] = 0;
}

extern "C" void kernel_launch(void* const* d_in, const int* in_sizes, int n_in,
                              void* d_out, int out_size, void* d_ws, size_t ws_size,
                              hipStream_t stream) {
  const float* src = (const float*)d_in[0];
  const float* E = (const float*)d_in[1];
  const float* w0g = (const float*)d_in[2];
  const float* b0g = (const float*)d_in[3];
  const float* w0c = (const float*)d_in[4];
  const float* b0c = (const float*)d_in[5];
  const float* w1g = (const float*)d_in[6];
  const float* b1g = (const float*)d_in[7];
  const float* w1c = (const float*)d_in[8];
  const float* b1c = (const float*)d_in[9];
  const float* cw = (const float*)d_in[10];
  const float* cb = (const float*)d_in[11];
  float* out = (float*)d_out;
  float* ws = (float*)d_ws;

  size_t off = 0;
  auto alloc = [&](size_t cnt) {  // cnt in floats
    float* p = ws + off;
    off += (cnt + 63) & ~(size_t)63;
    return p;
  };
  const int L0 = 64 * 72;   // 4608 (stride-72 layout, 8-aligned)
  const int L1 = 64 * 128;  // 8192
  _Float16* Ah = (_Float16*)alloc((size_t)KPAD * KPAD / 2);
  _Float16* Al = (_Float16*)alloc((size_t)KPAD * KPAD / 2);
  // X0 a/b ping-pong (4 contiguous buffers), then X1 a/b (4 contiguous)
  _Float16* X0ah = (_Float16*)alloc((size_t)KPAD * L0 / 2);
  _Float16* X0al = (_Float16*)alloc((size_t)KPAD * L0 / 2);
  _Float16* X0bh = (_Float16*)alloc((size_t)KPAD * L0 / 2);
  _Float16* X0bl = (_Float16*)alloc((size_t)KPAD * L0 / 2);
  _Float16* X1ah = (_Float16*)alloc((size_t)KPAD * L1 / 2);
  _Float16* X1al = (_Float16*)alloc((size_t)KPAD * L1 / 2);
  _Float16* X1bh = (_Float16*)alloc((size_t)KPAD * L1 / 2);
  _Float16* X1bl = (_Float16*)alloc((size_t)KPAD * L1 / 2);
  _Float16* Gh = (_Float16*)alloc((size_t)KPAD * L1 / 2);
  _Float16* Gl = (_Float16*)alloc((size_t)KPAD * L1 / 2);
  float* ZR = alloc((size_t)NN * BB * 64);
  float* h0 = alloc((size_t)NN * BB * 64);
  float* h1 = alloc((size_t)NN * BB * 64);
  if (off * sizeof(float) > ws_size) return;  // ws too small: fail loud (zeros)

  adj_kernel<<<NN, 256, 0, stream>>>(E, Ah, Al);
  {  // zero X0a..X0b span, X1a..X1b span, h0+h1 span
    size_t c0 = (size_t)4 * KPAD * L0;  // halves
    size_t c1 = (size_t)4 * KPAD * L1;
    size_t chh = (size_t)2 * NN * BB * 64;  // floats
    zero_u16<<<(int)((c0 + 255) / 256), 256, 0, stream>>>((unsigned short*)X0ah, c0);
    zero_u16<<<(int)((c1 + 255) / 256), 256, 0, stream>>>((unsigned short*)X1ah, c1);
    zero_f32<<<(int)((chh + 255) / 256), 256, 0, stream>>>(h0, chh);
  }

  const int gx0 = L0 / 128;  // 36
  const int gx1 = L1 / 128;  // 64
  const int sgrid = (NN * BB + 255) / 256;
  _Float16* np16 = nullptr;
  for (int t = 0; t < TT; ++t) {
    // ---- layer 0 ----
    src_kernel<<<sgrid, 256, 0, stream>>>(src, X0ah, X0al, X0bh, X0bl, t);
    mfma_gemm3<<<dim3(gx0, 7), 256, 0, stream>>>(Ah, Al, X0ah, X0al, Gh, Gl, L0);
    gconv_fused<72, 65, true><<<dim3(NN, 2), 256, 0, stream>>>(
        X0ah, X0al, Gh, Gl, E, w0g, b0g, nullptr, h0, ZR,
        X0bh, X0bl, 72, 1, np16, np16, 0, 0, np16, np16, 0, 0);
    mfma_gemm3<<<dim3(gx0, 7), 256, 0, stream>>>(Ah, Al, X0bh, X0bl, Gh, Gl, L0);
    gconv_fused<72, 65, false><<<dim3(NN, 1), 256, 0, stream>>>(
        X0bh, X0bl, Gh, Gl, E, w0c, b0c, ZR, h0, nullptr,
        X0ah, X0al, 72, 1, X1ah, X1al, 128, 0, X1bh, X1bl, 128, 0);
    // ---- layer 1 ----
    mfma_gemm3<<<dim3(gx1, 7), 256, 0, stream>>>(Ah, Al, X1ah, X1al, Gh, Gl, L1);
    gconv_fused<128, 128, true><<<dim3(NN, 2), 256, 0, stream>>>(
        X1ah, X1al, Gh, Gl, E, w1g, b1g, nullptr, h1, ZR,
        X1bh, X1bl, 128, 64, np16, np16, 0, 0, np16, np16, 0, 0);
    mfma_gemm3<<<dim3(gx1, 7), 256, 0, stream>>>(Ah, Al, X1bh, X1bl, Gh, Gl, L1);
    gconv_fused<128, 128, false><<<dim3(NN, 1), 256, 0, stream>>>(
        X1bh, X1bl, Gh, Gl, E, w1c, b1c, ZR, h1, nullptr,
        X1ah, X1al, 128, 64, np16, np16, 0, 0, np16, np16, 0, 0);
  }
  head_kernel<<<(BB * NN + 255) / 256, 256, 0, stream>>>(h1, cw, cb, out);
}